// Round 8
// baseline (895.915 us; speedup 1.0000x reference)
//
#include <hip/hip_runtime.h>

constexpr int D  = 256;
constexpr int K  = 8192;
constexpr int N  = 32768;   // B*S

typedef _Float16 f16;
typedef f16   f16x8  __attribute__((ext_vector_type(8)));
typedef float f32x16 __attribute__((ext_vector_type(16)));

__device__ __forceinline__ void gload_lds16(const void* g, void* l) {
    __builtin_amdgcn_global_load_lds(
        (const __attribute__((address_space(1))) unsigned int*)g,
        (__attribute__((address_space(3))) unsigned int*)l,
        16, 0, 0);
}

// ============================================================================
// Path A: fp16 3-split + 32x32x16 MFMA.  dot = zh*eh + (zl'*eh + zh*el')/1024
// cbt layout (transposed 16B chunks): chunk s in [0,64), code k:
//   s in [0,32):  eh elements d in [8s, 8s+8)
//   s in [32,64): el' elements d in [8(s-32), 8(s-32)+8)
//   stored at cbt[(s*8192 + k)*8 .. +8)
// R8: 4 waves x 64 rows = 256-row block (R7's 6-MFMA/2-read ratio) AND
// 2 blocks/CU = 2 waves/SIMD (R5's TLP) via K split into quarters.
// Grid 512 = 128 row-groups x 4 K-quarters; 64 k-tiles of 32 codes each.
// ============================================================================

__global__ void esq_kernel(const float* __restrict__ cb, float* __restrict__ esq) {
    const int lane = threadIdx.x & 63;
    const int code = (int)((blockIdx.x * (size_t)blockDim.x + threadIdx.x) >> 6);
    const float4 v = *reinterpret_cast<const float4*>(cb + (size_t)code * D + lane * 4);
    float s = v.x * v.x + v.y * v.y + v.z * v.z + v.w * v.w;
    #pragma unroll
    for (int m = 32; m >= 1; m >>= 1) s += __shfl_xor(s, m);
    if (lane == 0) esq[code] = s;
}

__global__ void cvt_t(const float* __restrict__ cb, f16* __restrict__ cbt) {
    const int g    = blockIdx.x * 256 + threadIdx.x;   // [0, 64*8192)
    const int s    = g >> 13;                          // chunk slot 0..63
    const int code = g & 8191;
    const float* src = cb + (size_t)code * D + (s & 31) * 8;
    const float4 a  = *reinterpret_cast<const float4*>(src);
    const float4 b2 = *reinterpret_cast<const float4*>(src + 4);
    const float vf[8] = {a.x, a.y, a.z, a.w, b2.x, b2.y, b2.z, b2.w};
    f16x8 o;
    if (s < 32) {
        #pragma unroll
        for (int e = 0; e < 8; ++e) o[e] = (f16)vf[e];
    } else {
        #pragma unroll
        for (int e = 0; e < 8; ++e) {
            f16 h = (f16)vf[e];
            o[e] = (f16)((vf[e] - (float)h) * 1024.0f);
        }
    }
    *reinterpret_cast<f16x8*>(cbt + ((size_t)s * 8192 + code) * 8) = o;
}

__launch_bounds__(256, 2)
__global__ void vq32(const float* __restrict__ z, const f16* __restrict__ cbt,
                     const float* __restrict__ esq,
                     float* __restrict__ wsv, int* __restrict__ wsi) {
    __shared__ f16 buf[2][16384];   // [64 slots][32 codes][8 f16] = 32 KB each

    const int tid  = threadIdx.x;
    const int w    = tid >> 6;       // 0..3
    const int l    = tid & 63;
    const int cid  = l & 31;
    const int half = l >> 5;
    const int rg    = blockIdx.x >> 2;
    const int kq    = blockIdx.x & 3;
    const int kbase = kq * 2048;     // each block scans 2048 codes = 64 k-tiles
    const size_t wrow0 = (size_t)rg * 256 + w * 64;   // wave owns 64 rows

    // ---- A fragments in registers: 2 tiles x 32 rows, 16 d-chunks of K=16 --
    // lane l holds A[row = tile*32 + (l&31)][k = u*16 + (l>>5)*8 + e]
    f16x8 zh0[16], zl0[16], zh1[16], zl1[16];
    #pragma unroll
    for (int t = 0; t < 2; ++t) {
        const float* zr = z + (wrow0 + t * 32 + cid) * D + half * 8;
        #pragma unroll
        for (int u = 0; u < 16; ++u) {
            float4 a  = *reinterpret_cast<const float4*>(zr + u * 16);
            float4 b2 = *reinterpret_cast<const float4*>(zr + u * 16 + 4);
            float vf[8] = {a.x, a.y, a.z, a.w, b2.x, b2.y, b2.z, b2.w};
            f16x8 h, lo;
            #pragma unroll
            for (int e = 0; e < 8; ++e) {
                f16 hh = (f16)vf[e];
                h[e]  = hh;
                lo[e] = (f16)((vf[e] - (float)hh) * 1024.0f);
            }
            if (t == 0) { zh0[u] = h; zl0[u] = lo; }
            else        { zh1[u] = h; zl1[u] = lo; }
        }
    }

    float minv0[16], minv1[16];
    int   mini0[16], mini1[16];
    #pragma unroll
    for (int g = 0; g < 16; ++g) {
        minv0[g] = 3.0e38f; mini0[g] = 0;
        minv1[g] = 3.0e38f; mini1[g] = 0;
    }

    f32x16 accA0 = (f32x16)0.0f, accB0 = (f32x16)0.0f;
    f32x16 accA1 = (f32x16)0.0f, accB1 = (f32x16)0.0f;

    // ---- staging: 8 gload_lds per thread covers 64 slots x 32 codes.
    // instr j, wave w, lane l -> granule G = j*256 + w*64 + l;
    // slot s = G>>5 = j*8 + w*2 + (l>>5), code c = l&31; dest linear 16B/lane.
    #pragma unroll
    for (int j = 0; j < 8; ++j) {
        const int s = j * 8 + w * 2 + half;
        gload_lds16(cbt + ((size_t)s * 8192 + kbase + cid) * 8,
                    &buf[0][(j * 256 + w * 64) * 8]);
    }
    __syncthreads();

    for (int kt = 0; kt < 64; ++kt) {
        const int  b        = kt & 1;
        const bool haveNext = (kt < 63);

        if (haveNext) {
            const int k0n = kbase + (kt + 1) * 32;
            #pragma unroll
            for (int j = 0; j < 8; ++j) {
                const int s = j * 8 + w * 2 + half;
                gload_lds16(cbt + ((size_t)s * 8192 + k0n + cid) * 8,
                            &buf[b ^ 1][(j * 256 + w * 64) * 8]);
            }
        }
        const float es = esq[kbase + kt * 32 + cid];

        // ---- compute: 32 ds_read_b128 + 96 MFMA per wave (6 MFMA / 2 reads) -
        const f16* Bp = &buf[b][0];
        __builtin_amdgcn_s_setprio(1);
        #pragma unroll
        for (int u = 0; u < 16; ++u) {
            f16x8 beh = *reinterpret_cast<const f16x8*>(Bp + ((2 * u + half) * 32 + cid) * 8);
            f16x8 bel = *reinterpret_cast<const f16x8*>(Bp + ((32 + 2 * u + half) * 32 + cid) * 8);
            accA0 = __builtin_amdgcn_mfma_f32_32x32x16_f16(zh0[u], beh, accA0, 0, 0, 0);
            accA1 = __builtin_amdgcn_mfma_f32_32x32x16_f16(zh1[u], beh, accA1, 0, 0, 0);
            accB0 = __builtin_amdgcn_mfma_f32_32x32x16_f16(zl0[u], beh, accB0, 0, 0, 0);
            accB1 = __builtin_amdgcn_mfma_f32_32x32x16_f16(zl1[u], beh, accB1, 0, 0, 0);
            accB0 = __builtin_amdgcn_mfma_f32_32x32x16_f16(zh0[u], bel, accB0, 0, 0, 0);
            accB1 = __builtin_amdgcn_mfma_f32_32x32x16_f16(zh1[u], bel, accB1, 0, 0, 0);
        }
        __builtin_amdgcn_s_setprio(0);

        // ---- epilogue: scores + running argmin (regs only) ----
        // C/D: col(code) = l&31, row = tile*32 + (g&3) + 8*(g>>2) + 4*(l>>5)
        const int c0 = kbase + kt * 32 + cid;
        #pragma unroll
        for (int g = 0; g < 16; ++g) {
            float d0 = fmaf(accB0[g], 0.0009765625f, accA0[g]);
            float s0 = fmaf(-2.0f, d0, es);
            if (s0 < minv0[g]) { minv0[g] = s0; mini0[g] = c0; }
            float d1 = fmaf(accB1[g], 0.0009765625f, accA1[g]);
            float s1 = fmaf(-2.0f, d1, es);
            if (s1 < minv1[g]) { minv1[g] = s1; mini1[g] = c0; }
        }
        accA0 = (f32x16)0.0f; accB0 = (f32x16)0.0f;
        accA1 = (f32x16)0.0f; accB1 = (f32x16)0.0f;

        if (haveNext) __syncthreads();   // drains DMA (vmcnt) + buffer swap
    }

    // ---- merge across 32 lanes per half (tie -> lower), write to ws ----
    #pragma unroll
    for (int t = 0; t < 2; ++t) {
        #pragma unroll
        for (int g = 0; g < 16; ++g) {
            float v   = t ? minv1[g] : minv0[g];
            int   idx = t ? mini1[g] : mini0[g];
            #pragma unroll
            for (int m = 1; m < 32; m <<= 1) {
                float ov = __shfl_xor(v, m);
                int   oi = __shfl_xor(idx, m);
                if (ov < v || (ov == v && oi < idx)) { v = ov; idx = oi; }
            }
            const size_t row = wrow0 + t * 32 + (g & 3) + 8 * (g >> 2) + 4 * half;
            if (cid == 0) {
                wsv[(size_t)kq * N + row] = v;
                wsi[(size_t)kq * N + row] = idx;
            }
        }
    }
}

// merge the 4 K-quarters + gather embedding; 16 lanes per row, 16 rows/block
__global__ void merge_gather(const float* __restrict__ wsv, const int* __restrict__ wsi,
                             const float* __restrict__ cb, float* __restrict__ out) {
    const int t   = threadIdx.x;
    const int r   = blockIdx.x * 16 + (t >> 4);
    const int l16 = t & 15;
    float v   = wsv[r];
    int   idx = wsi[r];
    #pragma unroll
    for (int q = 1; q < 4; ++q) {
        const float vq = wsv[(size_t)q * N + r];
        const int   iq = wsi[(size_t)q * N + r];
        // quarters ascend in code index; strict < keeps earliest on tie
        if (vq < v) { v = vq; idx = iq; }
    }
    if (l16 == 0) out[(size_t)N * D + r] = (float)idx;
    const float4* src = reinterpret_cast<const float4*>(cb + (size_t)idx * D);
    float4*       dst = reinterpret_cast<float4*>(out + (size_t)r * D);
    #pragma unroll
    for (int it = 0; it < 4; ++it) dst[l16 + 16 * it] = src[l16 + 16 * it];
}

// ============================================================================
// Path B (fallback if ws too small): round-1 fp32 kernels (verified exact).
// ============================================================================
constexpr int BM = 128, BN = 128, TD = 32, ZS = 260, CS = 36;

__launch_bounds__(256)
__global__ void vq_kernel(const float* __restrict__ z, const float* __restrict__ cb,
                          const float* __restrict__ esq, float* __restrict__ out) {
    __shared__ float zs[BM * ZS];
    __shared__ float cs[BN * CS];
    const int tid = threadIdx.x;
    const int tx  = tid & 15;
    const int ty  = tid >> 4;
    const size_t row0 = (size_t)blockIdx.x * BM;
    #pragma unroll
    for (int i = 0; i < 32; ++i) {
        int f  = tid + i * 256;
        int r  = f >> 6;
        int c4 = (f & 63) * 4;
        *reinterpret_cast<float4*>(&zs[r * ZS + c4]) =
            *reinterpret_cast<const float4*>(z + (row0 + r) * D + c4);
    }
    float minv[8]; int mini[8];
    #pragma unroll
    for (int i = 0; i < 8; ++i) { minv[i] = 3.4e38f; mini[i] = 0; }
    for (int k0 = 0; k0 < K; k0 += BN) {
        float acc[8][8];
        #pragma unroll
        for (int i = 0; i < 8; ++i)
            #pragma unroll
            for (int j = 0; j < 8; ++j) acc[i][j] = 0.0f;
        for (int dc = 0; dc < D; dc += TD) {
            __syncthreads();
            int c = tid >> 3, c4 = (tid & 7) * 4;
            #pragma unroll
            for (int i = 0; i < 4; ++i)
                *reinterpret_cast<float4*>(&cs[(c + 32 * i) * CS + c4]) =
                    *reinterpret_cast<const float4*>(cb + (size_t)(k0 + c + 32 * i) * D + dc + c4);
            __syncthreads();
            for (int d4 = 0; d4 < TD; d4 += 4) {
                float4 a[8], b[8];
                #pragma unroll
                for (int i = 0; i < 8; ++i)
                    a[i] = *reinterpret_cast<const float4*>(&zs[(ty + 16 * i) * ZS + dc + d4]);
                #pragma unroll
                for (int j = 0; j < 8; ++j)
                    b[j] = *reinterpret_cast<const float4*>(&cs[(tx + 16 * j) * CS + d4]);
                #pragma unroll
                for (int i = 0; i < 8; ++i)
                    #pragma unroll
                    for (int j = 0; j < 8; ++j)
                        acc[i][j] += a[i].x * b[j].x + a[i].y * b[j].y
                                   + a[i].z * b[j].z + a[i].w * b[j].w;
            }
        }
        #pragma unroll
        for (int j = 0; j < 8; ++j) {
            int code = k0 + tx + 16 * j;
            float es = esq[code];
            #pragma unroll
            for (int i = 0; i < 8; ++i) {
                float score = fmaf(-2.0f, acc[i][j], es);
                if (score < minv[i]) { minv[i] = score; mini[i] = code; }
            }
        }
    }
    float* out_idx = out + (size_t)N * D;
    #pragma unroll
    for (int i = 0; i < 8; ++i) {
        float v = minv[i]; int idx = mini[i];
        #pragma unroll
        for (int m = 1; m < 16; m <<= 1) {
            float ov = __shfl_xor(v, m);
            int   oi = __shfl_xor(idx, m);
            if (ov < v || (ov == v && oi < idx)) { v = ov; idx = oi; }
        }
        size_t row = row0 + ty + 16 * i;
        if (tx == 0) out_idx[row] = (float)idx;
        const float4* src = reinterpret_cast<const float4*>(cb + (size_t)idx * D);
        float4*       dst = reinterpret_cast<float4*>(out + row * D);
        #pragma unroll
        for (int t = 0; t < 4; ++t) dst[tx + 16 * t] = src[tx + 16 * t];
    }
}

extern "C" void kernel_launch(void* const* d_in, const int* in_sizes, int n_in,
                              void* d_out, int out_size, void* d_ws, size_t ws_size,
                              hipStream_t stream) {
    const float* z   = (const float*)d_in[0];
    const float* cb  = (const float*)d_in[1];
    float*       out = (float*)d_out;

    const size_t cbt_bytes = (size_t)K * 512 * sizeof(f16);   // 8 MB
    const size_t esq_bytes = (size_t)K * sizeof(float);
    const size_t wsv_bytes = (size_t)4 * N * sizeof(float);
    const size_t wsi_bytes = (size_t)4 * N * sizeof(int);
    const size_t need = cbt_bytes + esq_bytes + wsv_bytes + wsi_bytes;

    if (ws_size >= need) {
        char* p = (char*)d_ws;
        f16*   cbt  = (f16*)p;                 p += cbt_bytes;
        float* esqp = (float*)p;               p += esq_bytes;
        float* wsv  = (float*)p;               p += wsv_bytes;
        int*   wsi  = (int*)p;
        esq_kernel<<<(K * 64) / 256, 256, 0, stream>>>(cb, esqp);
        cvt_t<<<(K * 64) / 256, 256, 0, stream>>>(cb, cbt);
        vq32<<<512, 256, 0, stream>>>(z, cbt, esqp, wsv, wsi);
        merge_gather<<<N / 16, 256, 0, stream>>>(wsv, wsi, cb, out);
    } else {
        float* esqp = (float*)d_ws;
        esq_kernel<<<(K * 64) / 256, 256, 0, stream>>>(cb, esqp);
        vq_kernel<<<N / BM, 256, 0, stream>>>(z, cb, esqp, out);
    }
}

// Round 9
// 658.287 us; speedup vs baseline: 1.3610x; 1.3610x over previous
//
#include <hip/hip_runtime.h>

constexpr int D  = 256;
constexpr int K  = 8192;
constexpr int N  = 32768;   // B*S

typedef _Float16 f16;
typedef f16   f16x8  __attribute__((ext_vector_type(8)));
typedef float f32x16 __attribute__((ext_vector_type(16)));

__device__ __forceinline__ void gload_lds16(const void* g, void* l) {
    __builtin_amdgcn_global_load_lds(
        (const __attribute__((address_space(1))) unsigned int*)g,
        (__attribute__((address_space(3))) unsigned int*)l,
        16, 0, 0);
}

// setprio needs an immediate; pb is wave-uniform -> uniform cheap branch.
__device__ __forceinline__ void prio_hi(int pb) {
    if (pb) __builtin_amdgcn_s_setprio(2); else __builtin_amdgcn_s_setprio(1);
}
__device__ __forceinline__ void prio_lo(int pb) {
    if (pb) __builtin_amdgcn_s_setprio(1); else __builtin_amdgcn_s_setprio(0);
}

// ============================================================================
// Path A: fp16 3-split + 32x32x16 MFMA.  dot = zh*eh + (zl'*eh + zh*el')/1024
// cbt layout (transposed 16B chunks): chunk s in [0,64), code k:
//   s in [0,32):  eh elements d in [8s, 8s+8)
//   s in [32,64): el' elements d in [8(s-32), 8(s-32)+8)
//   stored at cbt[(s*8192 + k)*8 .. +8)
// R9 = R5 structure (verified 361us: 4 waves x 32 rows, 2 K-halves,
// 2x32KB LDS dbuf, 2 blocks/CU) +
//   (1) T15 double-banked accumulators: tile kt's argmin epilogue runs inside
//       tile kt+1's body (static bank selection via 2x-unrolled tile calls).
//   (2) block-parity base priority (leader/follower convoy-break).
// ============================================================================

__global__ void esq_kernel(const float* __restrict__ cb, float* __restrict__ esq) {
    const int lane = threadIdx.x & 63;
    const int code = (int)((blockIdx.x * (size_t)blockDim.x + threadIdx.x) >> 6);
    const float4 v = *reinterpret_cast<const float4*>(cb + (size_t)code * D + lane * 4);
    float s = v.x * v.x + v.y * v.y + v.z * v.z + v.w * v.w;
    #pragma unroll
    for (int m = 32; m >= 1; m >>= 1) s += __shfl_xor(s, m);
    if (lane == 0) esq[code] = s;
}

__global__ void cvt_t(const float* __restrict__ cb, f16* __restrict__ cbt) {
    const int g    = blockIdx.x * 256 + threadIdx.x;   // [0, 64*8192)
    const int s    = g >> 13;                          // chunk slot 0..63
    const int code = g & 8191;
    const float* src = cb + (size_t)code * D + (s & 31) * 8;
    const float4 a  = *reinterpret_cast<const float4*>(src);
    const float4 b2 = *reinterpret_cast<const float4*>(src + 4);
    const float vf[8] = {a.x, a.y, a.z, a.w, b2.x, b2.y, b2.z, b2.w};
    f16x8 o;
    if (s < 32) {
        #pragma unroll
        for (int e = 0; e < 8; ++e) o[e] = (f16)vf[e];
    } else {
        #pragma unroll
        for (int e = 0; e < 8; ++e) {
            f16 h = (f16)vf[e];
            o[e] = (f16)((vf[e] - (float)h) * 1024.0f);
        }
    }
    *reinterpret_cast<f16x8*>(cbt + ((size_t)s * 8192 + code) * 8) = o;
}

__launch_bounds__(256, 2)
__global__ void vq32(const float* __restrict__ z, const f16* __restrict__ cbt,
                     const float* __restrict__ esq,
                     float* __restrict__ wsv, int* __restrict__ wsi) {
    __shared__ f16 buf[2][16384];   // [64 slots][32 codes][8 f16] = 32 KB each

    const int tid  = threadIdx.x;
    const int w    = tid >> 6;
    const int l    = tid & 63;
    const int cid  = l & 31;
    const int half = l >> 5;
    const int rg    = blockIdx.x >> 1;
    const int kh    = blockIdx.x & 1;
    const int kbase = kh * 4096;
    const int pb    = (blockIdx.x >> 8) & 1;   // leader/follower parity
    const size_t wrow0 = (size_t)rg * 128 + w * 32;

    // ---- A fragments in registers: 32 rows, 16 d-chunks of K=16 ----
    // lane l holds A[row = l&31][k = u*16 + (l>>5)*8 + e]
    f16x8 zh[16], zl[16];
    {
        const float* zr = z + (wrow0 + cid) * D + half * 8;
        #pragma unroll
        for (int u = 0; u < 16; ++u) {
            float4 a  = *reinterpret_cast<const float4*>(zr + u * 16);
            float4 b2 = *reinterpret_cast<const float4*>(zr + u * 16 + 4);
            float vf[8] = {a.x, a.y, a.z, a.w, b2.x, b2.y, b2.z, b2.w};
            f16x8 h, lo;
            #pragma unroll
            for (int e = 0; e < 8; ++e) {
                f16 hh = (f16)vf[e];
                h[e]  = hh;
                lo[e] = (f16)((vf[e] - (float)hh) * 1024.0f);
            }
            zh[u] = h; zl[u] = lo;
        }
    }

    float minv[16];
    int   mini[16];
    #pragma unroll
    for (int g = 0; g < 16; ++g) { minv[g] = 3.0e38f; mini[g] = 0; }

    // two accumulator banks: tile kt uses bank kt&1; epilogue deferred one tile
    f32x16 accA0 = (f32x16)0.0f, accB0 = (f32x16)0.0f;
    f32x16 accA1 = (f32x16)0.0f, accB1 = (f32x16)0.0f;

    float es_prev = 0.0f;
    int   c0_prev = 0;

    // ---- prologue: stage k-tile 0 into buf[0] ----
    #pragma unroll
    for (int j = 0; j < 8; ++j) {
        const int s = w * 16 + 2 * j + half;
        gload_lds16(cbt + ((size_t)s * 8192 + kbase + cid) * 8,
                    &buf[0][(w * 16 + 2 * j) * 256]);
    }
    __syncthreads();

    // tile body: DMA next -> (epilogue prev bank, overlaps reads) -> MFMA -> barrier
    auto tile = [&](int KT, f32x16& AC, f32x16& BC, f32x16& AP, f32x16& BPk,
                    int FIRST, int LAST, const f16* Brd, f16* Bwr) {
        if (!LAST) {
            const int k0n = kbase + (KT + 1) * 32;
            #pragma unroll
            for (int j = 0; j < 8; ++j) {
                const int s = w * 16 + 2 * j + half;
                gload_lds16(cbt + ((size_t)s * 8192 + k0n + cid) * 8,
                            Bwr + (w * 16 + 2 * j) * 256);
            }
        }
        const float es_c = esq[kbase + KT * 32 + cid];
        const int   c0_c = kbase + KT * 32 + cid;
        if (!FIRST) {   // deferred epilogue of previous tile (reg-only VALU)
            #pragma unroll
            for (int g = 0; g < 16; ++g) {
                float d = fmaf(BPk[g], 0.0009765625f, AP[g]);
                float s = fmaf(-2.0f, d, es_prev);
                if (s < minv[g]) { minv[g] = s; mini[g] = c0_prev; }
            }
            AP  = (f32x16)0.0f;
            BPk = (f32x16)0.0f;
        }
        prio_hi(pb);
        #pragma unroll
        for (int u = 0; u < 16; ++u) {
            f16x8 beh = *reinterpret_cast<const f16x8*>(Brd + ((2 * u + half) * 32 + cid) * 8);
            f16x8 bel = *reinterpret_cast<const f16x8*>(Brd + ((32 + 2 * u + half) * 32 + cid) * 8);
            AC = __builtin_amdgcn_mfma_f32_32x32x16_f16(zh[u], beh, AC, 0, 0, 0);
            BC = __builtin_amdgcn_mfma_f32_32x32x16_f16(zl[u], beh, BC, 0, 0, 0);
            BC = __builtin_amdgcn_mfma_f32_32x32x16_f16(zh[u], bel, BC, 0, 0, 0);
        }
        prio_lo(pb);
        es_prev = es_c; c0_prev = c0_c;
        if (!LAST) __syncthreads();   // drains DMA (vmcnt) + buffer swap
    };

    tile(0, accA0, accB0, accA1, accB1, 1, 0, &buf[0][0], &buf[1][0]);
    for (int kt2 = 0; kt2 < 63; ++kt2) {
        tile(2 * kt2 + 1, accA1, accB1, accA0, accB0, 0, 0, &buf[1][0], &buf[0][0]);
        tile(2 * kt2 + 2, accA0, accB0, accA1, accB1, 0, 0, &buf[0][0], &buf[1][0]);
    }
    tile(127, accA1, accB1, accA0, accB0, 0, 1, &buf[1][0], &buf[0][0]);

    // final epilogue for tile 127 (bank 1)
    #pragma unroll
    for (int g = 0; g < 16; ++g) {
        float d = fmaf(accB1[g], 0.0009765625f, accA1[g]);
        float s = fmaf(-2.0f, d, es_prev);
        if (s < minv[g]) { minv[g] = s; mini[g] = c0_prev; }
    }

    // ---- merge across 32 lanes per half (tie -> lower), write to ws ----
    #pragma unroll
    for (int g = 0; g < 16; ++g) {
        float v   = minv[g];
        int   idx = mini[g];
        #pragma unroll
        for (int m = 1; m < 32; m <<= 1) {
            float ov = __shfl_xor(v, m);
            int   oi = __shfl_xor(idx, m);
            if (ov < v || (ov == v && oi < idx)) { v = ov; idx = oi; }
        }
        const size_t row = wrow0 + (g & 3) + 8 * (g >> 2) + 4 * half;
        if (cid == 0) {
            wsv[(size_t)kh * N + row] = v;
            wsi[(size_t)kh * N + row] = idx;
        }
    }
}

// merge the 2 K-halves + gather embedding; 16 lanes per row, 16 rows/block
__global__ void merge_gather(const float* __restrict__ wsv, const int* __restrict__ wsi,
                             const float* __restrict__ cb, float* __restrict__ out) {
    const int t   = threadIdx.x;
    const int r   = blockIdx.x * 16 + (t >> 4);
    const int l16 = t & 15;
    const float v0 = wsv[r], v1 = wsv[N + r];
    const int   i0 = wsi[r], i1 = wsi[N + r];
    // half-0 indices < half-1 indices, so tie (v1==v0) -> i0 = lower index
    const int idx = (v1 < v0) ? i1 : i0;
    if (l16 == 0) out[(size_t)N * D + r] = (float)idx;
    const float4* src = reinterpret_cast<const float4*>(cb + (size_t)idx * D);
    float4*       dst = reinterpret_cast<float4*>(out + (size_t)r * D);
    #pragma unroll
    for (int it = 0; it < 4; ++it) dst[l16 + 16 * it] = src[l16 + 16 * it];
}

// ============================================================================
// Path B (fallback if ws too small): round-1 fp32 kernels (verified exact).
// ============================================================================
constexpr int BM = 128, BN = 128, TD = 32, ZS = 260, CS = 36;

__launch_bounds__(256)
__global__ void vq_kernel(const float* __restrict__ z, const float* __restrict__ cb,
                          const float* __restrict__ esq, float* __restrict__ out) {
    __shared__ float zs[BM * ZS];
    __shared__ float cs[BN * CS];
    const int tid = threadIdx.x;
    const int tx  = tid & 15;
    const int ty  = tid >> 4;
    const size_t row0 = (size_t)blockIdx.x * BM;
    #pragma unroll
    for (int i = 0; i < 32; ++i) {
        int f  = tid + i * 256;
        int r  = f >> 6;
        int c4 = (f & 63) * 4;
        *reinterpret_cast<float4*>(&zs[r * ZS + c4]) =
            *reinterpret_cast<const float4*>(z + (row0 + r) * D + c4);
    }
    float minv[8]; int mini[8];
    #pragma unroll
    for (int i = 0; i < 8; ++i) { minv[i] = 3.4e38f; mini[i] = 0; }
    for (int k0 = 0; k0 < K; k0 += BN) {
        float acc[8][8];
        #pragma unroll
        for (int i = 0; i < 8; ++i)
            #pragma unroll
            for (int j = 0; j < 8; ++j) acc[i][j] = 0.0f;
        for (int dc = 0; dc < D; dc += TD) {
            __syncthreads();
            int c = tid >> 3, c4 = (tid & 7) * 4;
            #pragma unroll
            for (int i = 0; i < 4; ++i)
                *reinterpret_cast<float4*>(&cs[(c + 32 * i) * CS + c4]) =
                    *reinterpret_cast<const float4*>(cb + (size_t)(k0 + c + 32 * i) * D + dc + c4);
            __syncthreads();
            for (int d4 = 0; d4 < TD; d4 += 4) {
                float4 a[8], b[8];
                #pragma unroll
                for (int i = 0; i < 8; ++i)
                    a[i] = *reinterpret_cast<const float4*>(&zs[(ty + 16 * i) * ZS + dc + d4]);
                #pragma unroll
                for (int j = 0; j < 8; ++j)
                    b[j] = *reinterpret_cast<const float4*>(&cs[(tx + 16 * j) * CS + d4]);
                #pragma unroll
                for (int i = 0; i < 8; ++i)
                    #pragma unroll
                    for (int j = 0; j < 8; ++j)
                        acc[i][j] += a[i].x * b[j].x + a[i].y * b[j].y
                                   + a[i].z * b[j].z + a[i].w * b[j].w;
            }
        }
        #pragma unroll
        for (int j = 0; j < 8; ++j) {
            int code = k0 + tx + 16 * j;
            float es = esq[code];
            #pragma unroll
            for (int i = 0; i < 8; ++i) {
                float score = fmaf(-2.0f, acc[i][j], es);
                if (score < minv[i]) { minv[i] = score; mini[i] = code; }
            }
        }
    }
    float* out_idx = out + (size_t)N * D;
    #pragma unroll
    for (int i = 0; i < 8; ++i) {
        float v = minv[i]; int idx = mini[i];
        #pragma unroll
        for (int m = 1; m < 16; m <<= 1) {
            float ov = __shfl_xor(v, m);
            int   oi = __shfl_xor(idx, m);
            if (ov < v || (ov == v && oi < idx)) { v = ov; idx = oi; }
        }
        size_t row = row0 + ty + 16 * i;
        if (tx == 0) out_idx[row] = (float)idx;
        const float4* src = reinterpret_cast<const float4*>(cb + (size_t)idx * D);
        float4*       dst = reinterpret_cast<float4*>(out + row * D);
        #pragma unroll
        for (int t = 0; t < 4; ++t) dst[tx + 16 * t] = src[tx + 16 * t];
    }
}

extern "C" void kernel_launch(void* const* d_in, const int* in_sizes, int n_in,
                              void* d_out, int out_size, void* d_ws, size_t ws_size,
                              hipStream_t stream) {
    const float* z   = (const float*)d_in[0];
    const float* cb  = (const float*)d_in[1];
    float*       out = (float*)d_out;

    const size_t cbt_bytes = (size_t)K * 512 * sizeof(f16);   // 8 MB
    const size_t esq_bytes = (size_t)K * sizeof(float);
    const size_t wsv_bytes = (size_t)2 * N * sizeof(float);
    const size_t wsi_bytes = (size_t)2 * N * sizeof(int);
    const size_t need = cbt_bytes + esq_bytes + wsv_bytes + wsi_bytes;

    if (ws_size >= need) {
        char* p = (char*)d_ws;
        f16*   cbt  = (f16*)p;                 p += cbt_bytes;
        float* esqp = (float*)p;               p += esq_bytes;
        float* wsv  = (float*)p;               p += wsv_bytes;
        int*   wsi  = (int*)p;
        esq_kernel<<<(K * 64) / 256, 256, 0, stream>>>(cb, esqp);
        cvt_t<<<(K * 64) / 256, 256, 0, stream>>>(cb, cbt);
        vq32<<<512, 256, 0, stream>>>(z, cbt, esqp, wsv, wsi);
        merge_gather<<<N / 16, 256, 0, stream>>>(wsv, wsi, cb, out);
    } else {
        float* esqp = (float*)d_ws;
        esq_kernel<<<(K * 64) / 256, 256, 0, stream>>>(cb, esqp);
        vq_kernel<<<N / BM, 256, 0, stream>>>(z, cb, esqp, out);
    }
}

// Round 10
// 378.264 us; speedup vs baseline: 2.3685x; 1.7403x over previous
//
#include <hip/hip_runtime.h>

constexpr int D  = 256;
constexpr int K  = 8192;
constexpr int N  = 32768;   // B*S

typedef _Float16 f16;
typedef f16   f16x8  __attribute__((ext_vector_type(8)));
typedef float f32x16 __attribute__((ext_vector_type(16)));

__device__ __forceinline__ void gload_lds16(const void* g, void* l) {
    __builtin_amdgcn_global_load_lds(
        (const __attribute__((address_space(1))) unsigned int*)g,
        (__attribute__((address_space(3))) unsigned int*)l,
        16, 0, 0);
}

// ============================================================================
// Path A: fp16 3-split + 32x32x16 MFMA.  dot = zh*eh + (zl'*eh + zh*el')/1024
// cbt layout (transposed 16B chunks): chunk s in [0,64), code k:
//   s in [0,32):  eh elements d in [8s, 8s+8)
//   s in [32,64): el' elements d in [8(s-32), 8(s-32)+8)
//   stored at cbt[(s*8192 + k)*8 .. +8)
// R10 = R5 structure (verified 361us: 4 waves x 32 rows, 2 K-halves,
// 2x32KB LDS dbuf, 2 blocks/CU) + WAVE PHASE-STAGGER: wave w starts its
// u-loop at offset 4w (mod 16), turning the post-barrier read burst/drain
// convoy (LDS 3072 + MFMA 3072 serial) into streamed overlap.
// Static indexing via wave-uniform 4-way branch, fully unrolled arms.
// ============================================================================

__global__ void esq_kernel(const float* __restrict__ cb, float* __restrict__ esq) {
    const int lane = threadIdx.x & 63;
    const int code = (int)((blockIdx.x * (size_t)blockDim.x + threadIdx.x) >> 6);
    const float4 v = *reinterpret_cast<const float4*>(cb + (size_t)code * D + lane * 4);
    float s = v.x * v.x + v.y * v.y + v.z * v.z + v.w * v.w;
    #pragma unroll
    for (int m = 32; m >= 1; m >>= 1) s += __shfl_xor(s, m);
    if (lane == 0) esq[code] = s;
}

__global__ void cvt_t(const float* __restrict__ cb, f16* __restrict__ cbt) {
    const int g    = blockIdx.x * 256 + threadIdx.x;   // [0, 64*8192)
    const int s    = g >> 13;                          // chunk slot 0..63
    const int code = g & 8191;
    const float* src = cb + (size_t)code * D + (s & 31) * 8;
    const float4 a  = *reinterpret_cast<const float4*>(src);
    const float4 b2 = *reinterpret_cast<const float4*>(src + 4);
    const float vf[8] = {a.x, a.y, a.z, a.w, b2.x, b2.y, b2.z, b2.w};
    f16x8 o;
    if (s < 32) {
        #pragma unroll
        for (int e = 0; e < 8; ++e) o[e] = (f16)vf[e];
    } else {
        #pragma unroll
        for (int e = 0; e < 8; ++e) {
            f16 h = (f16)vf[e];
            o[e] = (f16)((vf[e] - (float)h) * 1024.0f);
        }
    }
    *reinterpret_cast<f16x8*>(cbt + ((size_t)s * 8192 + code) * 8) = o;
}

__launch_bounds__(256, 2)
__global__ void vq32(const float* __restrict__ z, const f16* __restrict__ cbt,
                     const float* __restrict__ esq,
                     float* __restrict__ wsv, int* __restrict__ wsi) {
    __shared__ f16 buf[2][16384];   // [64 slots][32 codes][8 f16] = 32 KB each

    const int tid  = threadIdx.x;
    const int w    = tid >> 6;
    const int l    = tid & 63;
    const int cid  = l & 31;
    const int half = l >> 5;
    const int rg    = blockIdx.x >> 1;
    const int kh    = blockIdx.x & 1;
    const int kbase = kh * 4096;
    const size_t wrow0 = (size_t)rg * 128 + w * 32;

    // ---- A fragments in registers: 32 rows, 16 d-chunks of K=16 ----
    // lane l holds A[row = l&31][k = u*16 + (l>>5)*8 + e]
    f16x8 zh[16], zl[16];
    {
        const float* zr = z + (wrow0 + cid) * D + half * 8;
        #pragma unroll
        for (int u = 0; u < 16; ++u) {
            float4 a  = *reinterpret_cast<const float4*>(zr + u * 16);
            float4 b2 = *reinterpret_cast<const float4*>(zr + u * 16 + 4);
            float vf[8] = {a.x, a.y, a.z, a.w, b2.x, b2.y, b2.z, b2.w};
            f16x8 h, lo;
            #pragma unroll
            for (int e = 0; e < 8; ++e) {
                f16 hh = (f16)vf[e];
                h[e]  = hh;
                lo[e] = (f16)((vf[e] - (float)hh) * 1024.0f);
            }
            zh[u] = h; zl[u] = lo;
        }
    }

    float minv[16];
    int   mini[16];
    #pragma unroll
    for (int g = 0; g < 16; ++g) { minv[g] = 3.0e38f; mini[g] = 0; }

    f32x16 accA = (f32x16)0.0f, accB = (f32x16)0.0f;

    // ---- staging: wave w DMAs slots [w*16, w*16+16); instr j covers 2 slots.
    // lane l -> slot (base+2j+(l>>5)), code (k0 + (l&31)); dest linear 1 KB.
    #pragma unroll
    for (int j = 0; j < 8; ++j) {
        const int s = w * 16 + 2 * j + half;
        gload_lds16(cbt + ((size_t)s * 8192 + kbase + cid) * 8,
                    &buf[0][(w * 16 + 2 * j) * 256]);
    }
    __syncthreads();

    for (int kt = 0; kt < 128; ++kt) {
        const int  b        = kt & 1;
        const bool haveNext = (kt < 127);

        if (haveNext) {
            const int k0n = kbase + (kt + 1) * 32;
            #pragma unroll
            for (int j = 0; j < 8; ++j) {
                const int s = w * 16 + 2 * j + half;
                gload_lds16(cbt + ((size_t)s * 8192 + k0n + cid) * 8,
                            &buf[b ^ 1][(w * 16 + 2 * j) * 256]);
            }
        }
        const float es = esq[kbase + kt * 32 + cid];

        // ---- compute: 32 ds_read_b128 + 48 MFMA per wave, phase-staggered ---
        const f16* Bp = &buf[b][0];
#define VQSTEP(UU)                                                                  \
        {                                                                           \
            f16x8 beh = *reinterpret_cast<const f16x8*>(                            \
                Bp + ((2 * (UU) + half) * 32 + cid) * 8);                           \
            f16x8 bel = *reinterpret_cast<const f16x8*>(                            \
                Bp + ((32 + 2 * (UU) + half) * 32 + cid) * 8);                      \
            accA = __builtin_amdgcn_mfma_f32_32x32x16_f16(zh[(UU)], beh, accA, 0, 0, 0); \
            accB = __builtin_amdgcn_mfma_f32_32x32x16_f16(zl[(UU)], beh, accB, 0, 0, 0); \
            accB = __builtin_amdgcn_mfma_f32_32x32x16_f16(zh[(UU)], bel, accB, 0, 0, 0); \
        }
#define VQPHASE(OFF)                                                                \
        {                                                                           \
            _Pragma("unroll")                                                       \
            for (int u = 0; u < 16; ++u) { const int uu = (u + (OFF)) & 15; VQSTEP(uu) } \
        }
        __builtin_amdgcn_s_setprio(1);
        if      (w == 0) VQPHASE(0)
        else if (w == 1) VQPHASE(4)
        else if (w == 2) VQPHASE(8)
        else             VQPHASE(12)
        __builtin_amdgcn_s_setprio(0);
#undef VQPHASE
#undef VQSTEP

        // ---- epilogue: scores + running argmin (regs only) ----
        // C/D: col(code) = l&31, row = (g&3) + 8*(g>>2) + 4*(l>>5)
        const int c0 = kbase + kt * 32 + cid;
        #pragma unroll
        for (int g = 0; g < 16; ++g) {
            float d = fmaf(accB[g], 0.0009765625f, accA[g]);
            float s = fmaf(-2.0f, d, es);
            if (s < minv[g]) { minv[g] = s; mini[g] = c0; }
        }
        accA = (f32x16)0.0f; accB = (f32x16)0.0f;

        if (haveNext) __syncthreads();   // drains DMA (vmcnt) + buffer swap
    }

    // ---- merge across 32 lanes per half (tie -> lower), write to ws ----
    #pragma unroll
    for (int g = 0; g < 16; ++g) {
        float v   = minv[g];
        int   idx = mini[g];
        #pragma unroll
        for (int m = 1; m < 32; m <<= 1) {
            float ov = __shfl_xor(v, m);
            int   oi = __shfl_xor(idx, m);
            if (ov < v || (ov == v && oi < idx)) { v = ov; idx = oi; }
        }
        const size_t row = wrow0 + (g & 3) + 8 * (g >> 2) + 4 * half;
        if (cid == 0) {
            wsv[(size_t)kh * N + row] = v;
            wsi[(size_t)kh * N + row] = idx;
        }
    }
}

// merge the 2 K-halves + gather embedding; 16 lanes per row, 16 rows/block
__global__ void merge_gather(const float* __restrict__ wsv, const int* __restrict__ wsi,
                             const float* __restrict__ cb, float* __restrict__ out) {
    const int t   = threadIdx.x;
    const int r   = blockIdx.x * 16 + (t >> 4);
    const int l16 = t & 15;
    const float v0 = wsv[r], v1 = wsv[N + r];
    const int   i0 = wsi[r], i1 = wsi[N + r];
    // half-0 indices < half-1 indices, so tie (v1==v0) -> i0 = lower index
    const int idx = (v1 < v0) ? i1 : i0;
    if (l16 == 0) out[(size_t)N * D + r] = (float)idx;
    const float4* src = reinterpret_cast<const float4*>(cb + (size_t)idx * D);
    float4*       dst = reinterpret_cast<float4*>(out + (size_t)r * D);
    #pragma unroll
    for (int it = 0; it < 4; ++it) dst[l16 + 16 * it] = src[l16 + 16 * it];
}

// ============================================================================
// Path B (fallback if ws too small): round-1 fp32 kernels (verified exact).
// ============================================================================
constexpr int BM = 128, BN = 128, TD = 32, ZS = 260, CS = 36;

__launch_bounds__(256)
__global__ void vq_kernel(const float* __restrict__ z, const float* __restrict__ cb,
                          const float* __restrict__ esq, float* __restrict__ out) {
    __shared__ float zs[BM * ZS];
    __shared__ float cs[BN * CS];
    const int tid = threadIdx.x;
    const int tx  = tid & 15;
    const int ty  = tid >> 4;
    const size_t row0 = (size_t)blockIdx.x * BM;
    #pragma unroll
    for (int i = 0; i < 32; ++i) {
        int f  = tid + i * 256;
        int r  = f >> 6;
        int c4 = (f & 63) * 4;
        *reinterpret_cast<float4*>(&zs[r * ZS + c4]) =
            *reinterpret_cast<const float4*>(z + (row0 + r) * D + c4);
    }
    float minv[8]; int mini[8];
    #pragma unroll
    for (int i = 0; i < 8; ++i) { minv[i] = 3.4e38f; mini[i] = 0; }
    for (int k0 = 0; k0 < K; k0 += BN) {
        float acc[8][8];
        #pragma unroll
        for (int i = 0; i < 8; ++i)
            #pragma unroll
            for (int j = 0; j < 8; ++j) acc[i][j] = 0.0f;
        for (int dc = 0; dc < D; dc += TD) {
            __syncthreads();
            int c = tid >> 3, c4 = (tid & 7) * 4;
            #pragma unroll
            for (int i = 0; i < 4; ++i)
                *reinterpret_cast<float4*>(&cs[(c + 32 * i) * CS + c4]) =
                    *reinterpret_cast<const float4*>(cb + (size_t)(k0 + c + 32 * i) * D + dc + c4);
            __syncthreads();
            for (int d4 = 0; d4 < TD; d4 += 4) {
                float4 a[8], b[8];
                #pragma unroll
                for (int i = 0; i < 8; ++i)
                    a[i] = *reinterpret_cast<const float4*>(&zs[(ty + 16 * i) * ZS + dc + d4]);
                #pragma unroll
                for (int j = 0; j < 8; ++j)
                    b[j] = *reinterpret_cast<const float4*>(&cs[(tx + 16 * j) * CS + d4]);
                #pragma unroll
                for (int i = 0; i < 8; ++i)
                    #pragma unroll
                    for (int j = 0; j < 8; ++j)
                        acc[i][j] += a[i].x * b[j].x + a[i].y * b[j].y
                                   + a[i].z * b[j].z + a[i].w * b[j].w;
            }
        }
        #pragma unroll
        for (int j = 0; j < 8; ++j) {
            int code = k0 + tx + 16 * j;
            float es = esq[code];
            #pragma unroll
            for (int i = 0; i < 8; ++i) {
                float score = fmaf(-2.0f, acc[i][j], es);
                if (score < minv[i]) { minv[i] = score; mini[i] = code; }
            }
        }
    }
    float* out_idx = out + (size_t)N * D;
    #pragma unroll
    for (int i = 0; i < 8; ++i) {
        float v = minv[i]; int idx = mini[i];
        #pragma unroll
        for (int m = 1; m < 16; m <<= 1) {
            float ov = __shfl_xor(v, m);
            int   oi = __shfl_xor(idx, m);
            if (ov < v || (ov == v && oi < idx)) { v = ov; idx = oi; }
        }
        size_t row = row0 + ty + 16 * i;
        if (tx == 0) out_idx[row] = (float)idx;
        const float4* src = reinterpret_cast<const float4*>(cb + (size_t)idx * D);
        float4*       dst = reinterpret_cast<float4*>(out + row * D);
        #pragma unroll
        for (int t = 0; t < 4; ++t) dst[tx + 16 * t] = src[tx + 16 * t];
    }
}

extern "C" void kernel_launch(void* const* d_in, const int* in_sizes, int n_in,
                              void* d_out, int out_size, void* d_ws, size_t ws_size,
                              hipStream_t stream) {
    const float* z   = (const float*)d_in[0];
    const float* cb  = (const float*)d_in[1];
    float*       out = (float*)d_out;

    const size_t cbt_bytes = (size_t)K * 512 * sizeof(f16);   // 8 MB
    const size_t esq_bytes = (size_t)K * sizeof(float);
    const size_t wsv_bytes = (size_t)2 * N * sizeof(float);
    const size_t wsi_bytes = (size_t)2 * N * sizeof(int);
    const size_t need = cbt_bytes + esq_bytes + wsv_bytes + wsi_bytes;

    if (ws_size >= need) {
        char* p = (char*)d_ws;
        f16*   cbt  = (f16*)p;                 p += cbt_bytes;
        float* esqp = (float*)p;               p += esq_bytes;
        float* wsv  = (float*)p;               p += wsv_bytes;
        int*   wsi  = (int*)p;
        esq_kernel<<<(K * 64) / 256, 256, 0, stream>>>(cb, esqp);
        cvt_t<<<(K * 64) / 256, 256, 0, stream>>>(cb, cbt);
        vq32<<<512, 256, 0, stream>>>(z, cbt, esqp, wsv, wsi);
        merge_gather<<<N / 16, 256, 0, stream>>>(wsv, wsi, cb, out);
    } else {
        float* esqp = (float*)d_ws;
        esq_kernel<<<(K * 64) / 256, 256, 0, stream>>>(cb, esqp);
        vq_kernel<<<N / BM, 256, 0, stream>>>(z, cb, esqp, out);
    }
}